// Round 5
// baseline (218.674 us; speedup 1.0000x reference)
//
#include <hip/hip_runtime.h>
#include <hip/hip_cooperative_groups.h>
#include <stdint.h>

namespace cg = cooperative_groups;

// Problem constants (fixed by reference setup_inputs)
#define N_NODES 8192
#define F_IN    256
#define F_OUT   64
#define N_EDGES 262144
#define LEAKY   0.2f
#define BN_EPSF 1e-5f
#define WPR     256            // bitmap words per row = N_NODES/32
#define MAXDEG  256            // Poisson(32): max row degree ~66; 256 is 8-sigma safe
#define WT_LD   260            // Wt stride: 260%32==4 -> b128 reads at 2-way floor (free)
#define SLOTS   8              // BN accumulator slots (atomic contention split)

typedef unsigned int u32;

__device__ __forceinline__ float lrelu(float x) {
    return fmaxf(x, LEAKY * x);   // slope in (0,1): monotone increasing
}

struct P1 {                        // phase 1: GEMM staging
    float Wt[F_OUT * WT_LD];       // 66,560 B transposed+padded W
    float hl[32 * F_IN];           // 32,768 B: 32 rows of h
};
struct P3 {                        // phases 3-4 (aliases P1; used only after grid sync)
    float f2l[N_NODES];            // 32,768 B: all f2 values
    float bnS[16][F_OUT];          // 4 KB   (rows 0-3 reused as mean/rstd/gamma/beta+bias)
    float bnQ[16][F_OUT];          // 4 KB
    int   nbr[16][MAXDEG];         // 16 KB: per-wave neighbor ids
    float fv [16][MAXDEG];         // 16 KB: per-wave f2 values
};

// One cooperative dispatch: 256 blocks (1/CU) x 1024 threads (16 waves).
__global__ __launch_bounds__(1024, 4) void k_all(
    const float* __restrict__ h, const int* __restrict__ ei,
    const float* __restrict__ W, const float* __restrict__ a,
    const float* __restrict__ bias, const float* __restrict__ gamma,
    const float* __restrict__ beta,
    float* __restrict__ hp, float* __restrict__ f1, float* __restrict__ f2,
    float* __restrict__ Mg, float* __restrict__ Dg, float* __restrict__ outr,
    float* __restrict__ Sacc, float* __restrict__ Qacc,
    u32* __restrict__ bm, float* __restrict__ out)
{
    __shared__ union { P1 p1; P3 p3; } S;
    cg::grid_group grid = cg::this_grid();
    const int tid = threadIdx.x;
    const int w = tid >> 6, lane = tid & 63;
    const int b = blockIdx.x;
    const int row0 = b * 32;

    // ---------------- Phase 1: zero bm/Sacc + hp = h@W, f1, f2 ----------------
    {
        const float4 z = {0.f, 0.f, 0.f, 0.f};
        float4* dst = reinterpret_cast<float4*>(bm + (size_t)b * (32 * WPR));
        dst[tid] = z; dst[tid + 1024] = z;                 // 32 KB slice
        if (b == 0 && tid < 256)                           // Sacc+Qacc = 4 KB contiguous
            reinterpret_cast<float4*>(Sacc)[tid] = z;
    }
    // W[k][o] -> Wt[o][k], 8x8 tiles: write banks 2-way (free)
#pragma unroll
    for (int t = 0; t < 16; ++t) {
        const int T = t * 16 + w;
        const int o = (T & 7) * 8 + (lane & 7);
        const int k = (T >> 3) * 8 + (lane >> 3);
        S.p1.Wt[o * WT_LD + k] = W[k * F_OUT + o];
    }
    {
        float4* hl4 = reinterpret_cast<float4*>(S.p1.hl);
        const float4* h4 = reinterpret_cast<const float4*>(h + (size_t)row0 * F_IN);
        hl4[tid] = h4[tid]; hl4[tid + 1024] = h4[tid + 1024];
    }
    __syncthreads();
    {
        const int o = lane;
        const float* hr0 = &S.p1.hl[(w * 2 + 0) * F_IN];
        const float* hr1 = &S.p1.hl[(w * 2 + 1) * F_IN];
        float acc0 = 0.f, acc1 = 0.f;
        for (int q = 0; q < 64; ++q) {
            const float4 wv = *reinterpret_cast<const float4*>(&S.p1.Wt[o * WT_LD + 4 * q]);
            const float4 h0 = *reinterpret_cast<const float4*>(&hr0[4 * q]);
            const float4 h1 = *reinterpret_cast<const float4*>(&hr1[4 * q]);
            acc0 += wv.x * h0.x + wv.y * h0.y + wv.z * h0.z + wv.w * h0.w;
            acc1 += wv.x * h1.x + wv.y * h1.y + wv.z * h1.z + wv.w * h1.w;
        }
        const int row = row0 + w * 2;
        hp[row * F_OUT + o] = acc0;
        hp[(row + 1) * F_OUT + o] = acc1;
        const float a1v = a[o], a2v = a[F_OUT + o];
        float p10 = acc0 * a1v, p20 = acc0 * a2v;
        float p11 = acc1 * a1v, p21 = acc1 * a2v;
#pragma unroll
        for (int off = 32; off; off >>= 1) {
            p10 += __shfl_xor(p10, off, 64);
            p20 += __shfl_xor(p20, off, 64);
            p11 += __shfl_xor(p11, off, 64);
            p21 += __shfl_xor(p21, off, 64);
        }
        if (o == 0) {
            f1[row] = p10; f2[row] = p20;
            f1[row + 1] = p11; f2[row + 1] = p21;
        }
    }
    grid.sync();

    // ---------------- Phase 2: edge scatter into bitmap (dedup) ----------------
    {
        const int e = b * 1024 + tid;
        const int r = ei[e];
        const int c = ei[N_EDGES + e];
        atomicOr(&bm[(size_t)r * WPR + (c >> 5)], 1u << (c & 31));
    }
    grid.sync();

    // ---------------- Phase 3: per-row softmax + gather, fused BN partials -----
    {
        float4* f2l4 = reinterpret_cast<float4*>(S.p3.f2l);
        const float4* f24 = reinterpret_cast<const float4*>(f2);
        f2l4[tid] = f24[tid]; f2l4[tid + 1024] = f24[tid + 1024];
    }
    __syncthreads();

    float myS = 0.f, myQ = 0.f;
    int* nb = S.p3.nbr[w];
    float* fvv = S.p3.fv[w];
    for (int rr = 0; rr < 2; ++rr) {
        const int row = row0 + w * 2 + rr;
        const uint4 bw = reinterpret_cast<const uint4*>(bm + (size_t)row * WPR)[lane];
        const int tot = __popc(bw.x) + __popc(bw.y) + __popc(bw.z) + __popc(bw.w);
        int pref = tot;                      // inclusive prefix over lanes
#pragma unroll
        for (int off = 1; off < 64; off <<= 1) {
            const int t2 = __shfl_up(pref, off, 64);
            if (lane >= off) pref += t2;
        }
        const int deg = __shfl(pref, 63, 64);
        int pos = pref - tot;                // exclusive
        float mymax = -1e30f;
        const u32 words[4] = {bw.x, bw.y, bw.z, bw.w};
#pragma unroll
        for (int i = 0; i < 4; ++i) {
            u32 bits = words[i];
            const int jbase = (lane * 4 + i) * 32;
            while (bits) {
                const int bit = __ffs(bits) - 1;
                bits &= bits - 1;
                const int j = jbase + bit;
                const float v = S.p3.f2l[j];
                mymax = fmaxf(mymax, v);
                if (pos < MAXDEG) { nb[pos] = j; fvv[pos] = v; }
                ++pos;
            }
        }
#pragma unroll
        for (int off = 32; off; off >>= 1)
            mymax = fmaxf(mymax, __shfl_xor(mymax, off, 64));

        const int dg = min(deg, MAXDEG);
        const float f1i = f1[row];
        float M = lrelu(f1i + mymax);
        float den0 = 0.f, den1 = 0.f, ac0 = 0.f, ac1 = 0.f;
        int n = 0;
        for (; n + 2 <= dg; n += 2) {
            const int j0 = nb[n], j1 = nb[n + 1];
            const float w0 = __expf(lrelu(f1i + fvv[n]) - M);
            const float w1 = __expf(lrelu(f1i + fvv[n + 1]) - M);
            den0 += w0;  den1 += w1;
            ac0 += w0 * hp[j0 * F_OUT + lane];
            ac1 += w1 * hp[j1 * F_OUT + lane];
        }
        if (n < dg) {
            const float w0 = __expf(lrelu(f1i + fvv[n]) - M);
            den0 += w0;
            ac0 += w0 * hp[nb[n] * F_OUT + lane];
        }
        float den = den0 + den1;
        float v = (ac0 + ac1) / den;
        if (dg == 0) { den = 1.f; M = 0.f; v = 0.f; }   // degenerate guard (P ~ e^-32)
        outr[row * F_OUT + lane] = v;
        if (lane == 0) { Mg[row] = M; Dg[row] = den; }
        myS += v; myQ += v * v;
    }
    S.p3.bnS[w][lane] = myS;
    S.p3.bnQ[w][lane] = myQ;
    __syncthreads();
    if (tid < F_OUT) {
        float s = 0.f, q = 0.f;
#pragma unroll
        for (int k = 0; k < 16; ++k) { s += S.p3.bnS[k][tid]; q += S.p3.bnQ[k][tid]; }
        const int slot = b & (SLOTS - 1);
        atomicAdd(&Sacc[slot * F_OUT + tid], s);
        atomicAdd(&Qacc[slot * F_OUT + tid], q);
    }
    grid.sync();

    // ---------------- Phase 4: BN finalize+apply (block-local rows) + alpha ----
    if (tid < F_OUT) {
        float s = 0.f, q = 0.f;
#pragma unroll
        for (int k = 0; k < SLOTS; ++k) { s += Sacc[k * F_OUT + tid]; q += Qacc[k * F_OUT + tid]; }
        const float mean = s * (1.f / N_NODES);
        const float var = q * (1.f / N_NODES) - mean * mean;
        S.p3.bnS[0][tid] = mean;
        S.p3.bnS[1][tid] = rsqrtf(var + BN_EPSF);
        S.p3.bnS[2][tid] = gamma[tid];
        S.p3.bnS[3][tid] = beta[tid] + bias[tid];
    }
    __syncthreads();
    if (tid < 512) {                              // this block's 2048 outr floats
        const int gid = b * 512 + tid;            // float4 index
        const float4 ov = reinterpret_cast<const float4*>(outr)[gid];
        const int o0 = (gid & 15) * 4;
        float4 res;
        res.x = (ov.x - S.p3.bnS[0][o0 + 0]) * S.p3.bnS[1][o0 + 0] * S.p3.bnS[2][o0 + 0] + S.p3.bnS[3][o0 + 0];
        res.y = (ov.y - S.p3.bnS[0][o0 + 1]) * S.p3.bnS[1][o0 + 1] * S.p3.bnS[2][o0 + 1] + S.p3.bnS[3][o0 + 1];
        res.z = (ov.z - S.p3.bnS[0][o0 + 2]) * S.p3.bnS[1][o0 + 2] * S.p3.bnS[2][o0 + 2] + S.p3.bnS[3][o0 + 2];
        res.w = (ov.w - S.p3.bnS[0][o0 + 3]) * S.p3.bnS[1][o0 + 3] * S.p3.bnS[2][o0 + 3] + S.p3.bnS[3][o0 + 3];
        reinterpret_cast<float4*>(out)[gid] = res;
    }
    {
        const int e = b * 1024 + tid;
        const int r = ei[e];
        const int c = ei[N_EDGES + e];
        out[N_NODES * F_OUT + e] = __expf(lrelu(f1[r] + S.p3.f2l[c]) - Mg[r]) / Dg[r];
    }
}

extern "C" void kernel_launch(void* const* d_in, const int* in_sizes, int n_in,
                              void* d_out, int out_size, void* d_ws, size_t ws_size,
                              hipStream_t stream) {
    const float* h     = (const float*)d_in[0];
    const int*   ei    = (const int*)  d_in[1];
    const float* W     = (const float*)d_in[2];
    const float* a     = (const float*)d_in[3];
    const float* bias  = (const float*)d_in[4];
    const float* gamma = (const float*)d_in[5];
    const float* beta  = (const float*)d_in[6];
    float* out = (float*)d_out;

    char* ws = (char*)d_ws;
    float* hp    = (float*)(ws + 0);          // 2 MB
    float* f1    = (float*)(ws + 2097152);    // 32 KB
    float* f2    = (float*)(ws + 2129920);    // 32 KB
    float* Mg    = (float*)(ws + 2162688);    // 32 KB
    float* Dg    = (float*)(ws + 2195456);    // 32 KB
    float* outr  = (float*)(ws + 2228224);    // 2 MB
    float* Sacc  = (float*)(ws + 4325376);    // 2 KB (8 slots x 64)  } zeroed as one
    float* Qacc  = (float*)(ws + 4327424);    // 2 KB                 } 4 KB range
    u32*   bm    = (u32*)  (ws + 4329472);    // 8 MB
    if (ws_size < (size_t)4329472 + (size_t)N_NODES * WPR * 4) return;

    void* args[] = {(void*)&h, (void*)&ei, (void*)&W, (void*)&a, (void*)&bias,
                    (void*)&gamma, (void*)&beta, (void*)&hp, (void*)&f1, (void*)&f2,
                    (void*)&Mg, (void*)&Dg, (void*)&outr, (void*)&Sacc, (void*)&Qacc,
                    (void*)&bm, (void*)&out};
    hipLaunchCooperativeKernel((void*)k_all, dim3(256), dim3(1024), args, 0, stream);
}

// Round 6
// 122.235 us; speedup vs baseline: 1.7890x; 1.7890x over previous
//
#include <hip/hip_runtime.h>
#include <stdint.h>

// Problem constants (fixed by reference setup_inputs)
#define N_NODES 8192
#define F_IN    256
#define F_OUT   64
#define N_EDGES 262144
#define LEAKY   0.2f
#define BN_EPSF 1e-5f
#define WPR     256            // bitmap words per row = N_NODES/32
#define MAXDEG  256            // Poisson(32): max row degree ~66; 256 is 8-sigma safe
#define WT_LD   260            // Wt stride: start-bank 4(o+q)%32 == canonical float4 pattern
#define SLOTS   8              // BN accumulator slots (atomic contention split)

typedef unsigned int u32;

__device__ __forceinline__ float lrelu(float x) {
    return fmaxf(x, LEAKY * x);   // slope in (0,1): monotone increasing
}

// D1: bitmap zero + Sacc/Qacc zero + hp = h@W, f1 = hp@a1, f2 = hp@a2.
// 256 blocks (1/CU), 4 waves x 8 rows. W transposed in LDS (reads are the
// canonical float4 bank pattern); h rows read via the SCALAR pipe
// (wave-uniform addresses -> s_load_dwordx4), so the GEMM loop issues
// 1 LDS b128 + 8 SMEM loads + 32 VALU fma per q -- no LDS bottleneck.
__global__ __launch_bounds__(256) void k_pre(
    const float* __restrict__ h, const float* __restrict__ W, const float* __restrict__ a,
    float* __restrict__ hp, float* __restrict__ f1, float* __restrict__ f2,
    u32* __restrict__ bm, float* __restrict__ Sacc)
{
    __shared__ float Wt[F_OUT * WT_LD];   // 66,560 B (transposed, padded)
    const int tid = threadIdx.x;
    const int w = tid >> 6, lane = tid & 63;
    const int b = blockIdx.x;

    // Zero this block's 32KB bitmap slice (float4 stores)
    {
        const float4 z = {0.f, 0.f, 0.f, 0.f};
        float4* dst = reinterpret_cast<float4*>(bm + (size_t)b * 8192);
#pragma unroll
        for (int p = 0; p < 8; ++p) dst[tid + p * 256] = z;
        if (b == 0 && tid < 256)   // Sacc+Qacc = 4 KB contiguous
            reinterpret_cast<float4*>(Sacc)[tid] = z;
    }

    // Transpose W[k][o] -> Wt[o][k], 8x8 tiles: write banks ~2-way (free)
#pragma unroll
    for (int t = 0; t < 64; ++t) {
        const int T = t * 4 + w;
        const int o = (T & 7) * 8 + (lane & 7);
        const int k = (T >> 3) * 8 + (lane >> 3);
        Wt[o * WT_LD + k] = W[k * F_OUT + o];
    }
    __syncthreads();

    const int row0 = b * 32;
    // Force wave-uniform h base so the compiler proves uniformity -> s_load
    const int wu = __builtin_amdgcn_readfirstlane(w);
    const float* hb = h + (size_t)(row0 + wu * 8) * F_IN;
    const int o = lane;

    float acc[8] = {0.f, 0.f, 0.f, 0.f, 0.f, 0.f, 0.f, 0.f};
    for (int q = 0; q < 64; ++q) {
        const float4 wv = *reinterpret_cast<const float4*>(&Wt[o * WT_LD + 4 * q]);
#pragma unroll
        for (int r = 0; r < 8; ++r) {
            const float4 hq = *reinterpret_cast<const float4*>(&hb[r * F_IN + 4 * q]);
            acc[r] += wv.x * hq.x + wv.y * hq.y + wv.z * hq.z + wv.w * hq.w;
        }
    }

    const float a1 = a[o], a2 = a[F_OUT + o];
#pragma unroll
    for (int r = 0; r < 8; ++r) {
        const int row = row0 + wu * 8 + r;
        hp[row * F_OUT + o] = acc[r];
        float p1 = acc[r] * a1;
        float p2 = acc[r] * a2;
#pragma unroll
        for (int off = 32; off; off >>= 1) {
            p1 += __shfl_xor(p1, off, 64);
            p2 += __shfl_xor(p2, off, 64);
        }
        if (o == 0) { f1[row] = p1; f2[row] = p2; }
    }
}

// D2: adjacency bitmap (device-scope atomics dedup duplicate edges)
__global__ __launch_bounds__(256) void k_adj(const int* __restrict__ ei, u32* __restrict__ bm)
{
    const int e = blockIdx.x * 256 + threadIdx.x;
    const int r = ei[e];
    const int c = ei[N_EDGES + e];
    atomicOr(&bm[(size_t)r * WPR + (c >> 5)], 1u << (c & 31));
}

// D3: 1 wave per row (2048 blocks x 4 waves): uint4 bitmap read + shfl
// prefix-sum compaction -> row max -> softmax denom + weighted hp gather
// (unroll-4 for MLP), fused BN partials.
__global__ __launch_bounds__(256) void k_attn(
    const u32* __restrict__ bm, const float* __restrict__ hp,
    const float* __restrict__ f1g, const float* __restrict__ f2g,
    float* __restrict__ Mg, float* __restrict__ Dg, float* __restrict__ outr,
    float* __restrict__ Sacc, float* __restrict__ Qacc)
{
    __shared__ int   nbr[4][MAXDEG];   // 4 KB
    __shared__ float fv [4][MAXDEG];   // 4 KB
    __shared__ float bnS[4][F_OUT], bnQ[4][F_OUT];
    const int tid = threadIdx.x;
    const int w = tid >> 6, lane = tid & 63;
    const int row = blockIdx.x * 4 + w;

    // uint4 bitmap read: lane covers words 4*lane .. 4*lane+3
    const uint4 bw = reinterpret_cast<const uint4*>(bm + (size_t)row * WPR)[lane];
    const int tot = __popc(bw.x) + __popc(bw.y) + __popc(bw.z) + __popc(bw.w);
    int pref = tot;                      // inclusive prefix over lanes
#pragma unroll
    for (int off = 1; off < 64; off <<= 1) {
        const int t2 = __shfl_up(pref, off, 64);
        if (lane >= off) pref += t2;
    }
    const int deg0 = __shfl(pref, 63, 64);
    int pos = pref - tot;                // exclusive
    float mymax = -1e30f;
    const u32 words[4] = {bw.x, bw.y, bw.z, bw.w};
    int* nb = nbr[w];
    float* fvv = fv[w];
#pragma unroll
    for (int i = 0; i < 4; ++i) {
        u32 bits = words[i];
        const int jbase = (lane * 4 + i) * 32;
        while (bits) {
            const int bit = __ffs(bits) - 1;
            bits &= bits - 1;
            const int j = jbase + bit;
            const float v = f2g[j];      // 32 KB table: L1-resident
            mymax = fmaxf(mymax, v);
            if (pos < MAXDEG) { nb[pos] = j; fvv[pos] = v; }
            ++pos;
        }
    }
#pragma unroll
    for (int off = 32; off; off >>= 1)
        mymax = fmaxf(mymax, __shfl_xor(mymax, off, 64));

    const int dg = min(deg0, MAXDEG);
    const float f1i = f1g[row];
    float M = lrelu(f1i + mymax);

    // unroll-4: independent accumulators, 4 gathers in flight
    float den0 = 0.f, den1 = 0.f, den2 = 0.f, den3 = 0.f;
    float ac0 = 0.f, ac1 = 0.f, ac2 = 0.f, ac3 = 0.f;
    int n = 0;
    for (; n + 4 <= dg; n += 4) {
        const int j0 = nb[n], j1 = nb[n + 1], j2 = nb[n + 2], j3 = nb[n + 3];
        const float w0 = __expf(lrelu(f1i + fvv[n]) - M);
        const float w1 = __expf(lrelu(f1i + fvv[n + 1]) - M);
        const float w2 = __expf(lrelu(f1i + fvv[n + 2]) - M);
        const float w3 = __expf(lrelu(f1i + fvv[n + 3]) - M);
        den0 += w0; den1 += w1; den2 += w2; den3 += w3;
        ac0 += w0 * hp[j0 * F_OUT + lane];
        ac1 += w1 * hp[j1 * F_OUT + lane];
        ac2 += w2 * hp[j2 * F_OUT + lane];
        ac3 += w3 * hp[j3 * F_OUT + lane];
    }
    for (; n < dg; ++n) {
        const float w0 = __expf(lrelu(f1i + fvv[n]) - M);
        den0 += w0;
        ac0 += w0 * hp[nb[n] * F_OUT + lane];
    }
    float den = (den0 + den1) + (den2 + den3);
    float v = ((ac0 + ac1) + (ac2 + ac3)) / den;
    if (dg == 0) { den = 1.f; M = 0.f; v = 0.f; }   // degenerate guard (P ~ e^-32)

    outr[row * F_OUT + lane] = v;
    if (lane == 0) { Mg[row] = M; Dg[row] = den; }

    // fused BN partials: block-level feature sums, one coalesced atomic per block
    bnS[w][lane] = v;
    bnQ[w][lane] = v * v;
    __syncthreads();
    if (w == 0) {
        const float s = bnS[0][lane] + bnS[1][lane] + bnS[2][lane] + bnS[3][lane];
        const float q = bnQ[0][lane] + bnQ[1][lane] + bnQ[2][lane] + bnQ[3][lane];
        const int slot = blockIdx.x & (SLOTS - 1);
        atomicAdd(&Sacc[slot * F_OUT + lane], s);
        atomicAdd(&Qacc[slot * F_OUT + lane], q);
    }
}

// D4: blocks [0,512) = BN finalize+apply (float4); blocks [512,1536) = alpha.
__global__ __launch_bounds__(256) void k_post(
    const float* __restrict__ outr, const float* __restrict__ Sacc,
    const float* __restrict__ Qacc, const float* __restrict__ gamma,
    const float* __restrict__ beta, const float* __restrict__ bias,
    const int* __restrict__ ei, const float* __restrict__ f1g,
    const float* __restrict__ f2g, const float* __restrict__ Mg,
    const float* __restrict__ Dg, float* __restrict__ out)
{
    const int tid = threadIdx.x;
    if (blockIdx.x < 512) {
        __shared__ float sm[F_OUT], sr[F_OUT], sg[F_OUT], sb[F_OUT];
        if (tid < F_OUT) {
            float s = 0.f, q = 0.f;
#pragma unroll
            for (int k = 0; k < SLOTS; ++k) {
                s += Sacc[k * F_OUT + tid];
                q += Qacc[k * F_OUT + tid];
            }
            const float mean = s * (1.f / N_NODES);
            const float var = q * (1.f / N_NODES) - mean * mean;
            sm[tid] = mean;
            sr[tid] = rsqrtf(var + BN_EPSF);
            sg[tid] = gamma[tid];
            sb[tid] = beta[tid] + bias[tid];
        }
        __syncthreads();
        const int gid = blockIdx.x * 256 + tid;          // float4 index
        const float4 ov = reinterpret_cast<const float4*>(outr)[gid];
        const int o0 = (gid & 15) * 4;
        float4 res;
        res.x = (ov.x - sm[o0 + 0]) * sr[o0 + 0] * sg[o0 + 0] + sb[o0 + 0];
        res.y = (ov.y - sm[o0 + 1]) * sr[o0 + 1] * sg[o0 + 1] + sb[o0 + 1];
        res.z = (ov.z - sm[o0 + 2]) * sr[o0 + 2] * sg[o0 + 2] + sb[o0 + 2];
        res.w = (ov.w - sm[o0 + 3]) * sr[o0 + 3] * sg[o0 + 3] + sb[o0 + 3];
        reinterpret_cast<float4*>(out)[gid] = res;
    } else {
        const int e = (blockIdx.x - 512) * 256 + tid;
        const int r = ei[e];
        const int c = ei[N_EDGES + e];
        out[N_NODES * F_OUT + e] = __expf(lrelu(f1g[r] + f2g[c]) - Mg[r]) / Dg[r];
    }
}

extern "C" void kernel_launch(void* const* d_in, const int* in_sizes, int n_in,
                              void* d_out, int out_size, void* d_ws, size_t ws_size,
                              hipStream_t stream) {
    const float* h     = (const float*)d_in[0];
    const int*   ei    = (const int*)  d_in[1];
    const float* W     = (const float*)d_in[2];
    const float* a     = (const float*)d_in[3];
    const float* bias  = (const float*)d_in[4];
    const float* gamma = (const float*)d_in[5];
    const float* beta  = (const float*)d_in[6];
    float* out = (float*)d_out;

    char* ws = (char*)d_ws;
    float* hp    = (float*)(ws + 0);          // 2 MB
    float* f1    = (float*)(ws + 2097152);    // 32 KB
    float* f2    = (float*)(ws + 2129920);    // 32 KB
    float* Mg    = (float*)(ws + 2162688);    // 32 KB
    float* Dg    = (float*)(ws + 2195456);    // 32 KB
    float* outr  = (float*)(ws + 2228224);    // 2 MB
    float* Sacc  = (float*)(ws + 4325376);    // 2 KB (8 slots x 64)  } zeroed as one
    float* Qacc  = (float*)(ws + 4327424);    // 2 KB                 } 4 KB range
    u32*   bm    = (u32*)  (ws + 4329472);    // 8 MB
    if (ws_size < (size_t)4329472 + (size_t)N_NODES * WPR * 4) return;

    k_pre <<<256,  256, 0, stream>>>(h, W, a, hp, f1, f2, bm, Sacc);
    k_adj <<<N_EDGES / 256, 256, 0, stream>>>(ei, bm);
    k_attn<<<N_NODES / 4, 256, 0, stream>>>(bm, hp, f1, f2, Mg, Dg, outr, Sacc, Qacc);
    k_post<<<1536, 256, 0, stream>>>(outr, Sacc, Qacc, gamma, beta, bias,
                                     ei, f1, f2, Mg, Dg, out);
}